// Round 1
// baseline (147.771 us; speedup 1.0000x reference)
//
#include <hip/hip_runtime.h>

// out = 2 * heatmap_loss (offset term cancels: o / stopgrad(o/h) == h).
// heatmap_loss = sum_all(w * huber(pred,gt)) / 16  ->  out = sum/8.

__device__ __forceinline__ float hterm(float p, float g) {
    float err  = fabsf(p - g);
    float quad = fminf(err, 1.0f);      // clip(err, 0, delta=1)
    float lin  = err - quad;
    float h    = 0.5f * quad * quad + lin;
    float w    = (g != 0.0f) ? 1.5f : 0.6f;
    return w * h;
}

__device__ __forceinline__ float hterm4(float4 p, float4 g) {
    return hterm(p.x, g.x) + hterm(p.y, g.y) + hterm(p.z, g.z) + hterm(p.w, g.w);
}

// Latency-bound fix: 4096 blocks (16/CU -> 2 co-resident rounds of 8, full
// 32 waves/CU) and ALL loads issued before any consumption (8 outstanding
// global_load_dwordx4 per wave, 32 payload VGPRs -- stays under the 64-VGPR
// / 8-waves-per-SIMD occupancy cliff, enforced by __launch_bounds__).
#define PAIRS 4

__global__ __launch_bounds__(256, 8) void heatmap_reduce_kernel(
        const float4* __restrict__ pred,
        const float4* __restrict__ gt,
        float* __restrict__ partial, int stride) {
    const int tid = blockIdx.x * 256 + threadIdx.x;

    float4 p[PAIRS], g[PAIRS];

    // Issue all 8 loads up-front; compiler emits 8 global_load_dwordx4 and
    // drains them with staged vmcnt waits as pairs are consumed.
    #pragma unroll
    for (int j = 0; j < PAIRS; ++j) p[j] = pred[tid + j * stride];
    #pragma unroll
    for (int j = 0; j < PAIRS; ++j) g[j] = gt[tid + j * stride];

    float acc = 0.0f;
    #pragma unroll
    for (int j = 0; j < PAIRS; ++j)
        acc += hterm4(p[j], g[j]);

    #pragma unroll
    for (int off = 32; off > 0; off >>= 1)
        acc += __shfl_down(acc, off, 64);

    __shared__ float wsum[4];
    int lane = threadIdx.x & 63;
    int wave = threadIdx.x >> 6;
    if (lane == 0) wsum[wave] = acc;
    __syncthreads();

    if (threadIdx.x == 0)
        partial[blockIdx.x] = wsum[0] + wsum[1] + wsum[2] + wsum[3];
}

__global__ __launch_bounds__(256) void finalize_kernel(
        const float4* __restrict__ partial4, float* __restrict__ out, int nblocks4) {
    float s = 0.0f;
    for (int i = threadIdx.x; i < nblocks4; i += 256) {
        float4 v = partial4[i];
        s += (v.x + v.y) + (v.z + v.w);
    }

    #pragma unroll
    for (int off = 32; off > 0; off >>= 1)
        s += __shfl_down(s, off, 64);

    __shared__ float wsum[4];
    int lane = threadIdx.x & 63;
    int wave = threadIdx.x >> 6;
    if (lane == 0) wsum[wave] = s;
    __syncthreads();

    if (threadIdx.x == 0)
        out[0] = (wsum[0] + wsum[1] + wsum[2] + wsum[3]) * 0.125f;
}

extern "C" void kernel_launch(void* const* d_in, const int* in_sizes, int n_in,
                              void* d_out, int out_size, void* d_ws, size_t ws_size,
                              hipStream_t stream) {
    const float* pred = (const float*)d_in[0];
    const float* gt   = (const float*)d_in[1];
    float* out     = (float*)d_out;
    float* partial = (float*)d_ws;

    int n  = in_sizes[0];        // 2*8*64*128*128 = 16,777,216
    int n4 = n >> 2;             // 4,194,304 float4s

    const int block  = 256;
    const int grid   = n4 / (block * PAIRS);   // 4096 blocks: 16/CU, 2 rounds of 8
    const int stride = grid * block;           // float4 stride between j-steps

    heatmap_reduce_kernel<<<grid, block, 0, stream>>>(
        (const float4*)pred, (const float4*)gt, partial, stride);

    finalize_kernel<<<1, block, 0, stream>>>(
        (const float4*)partial, out, grid / 4);
}

// Round 2
// 144.963 us; speedup vs baseline: 1.0194x; 1.0194x over previous
//
#include <hip/hip_runtime.h>

// out = 2 * heatmap_loss (offset term cancels: o / stopgrad(o/h) == h).
// heatmap_loss = sum_all(w * huber(pred,gt)) / 16  ->  out = sum/8.

__device__ __forceinline__ float hterm(float p, float g) {
    float err  = fabsf(p - g);
    float quad = fminf(err, 1.0f);      // clip(err, 0, delta=1)
    float lin  = err - quad;
    float h    = 0.5f * quad * quad + lin;
    float w    = (g != 0.0f) ? 1.5f : 0.6f;
    return w * h;
}

__device__ __forceinline__ float hterm4(float4 p, float4 g) {
    return hterm(p.x, g.x) + hterm(p.y, g.y) + hterm(p.z, g.z) + hterm(p.w, g.w);
}

// Miss-level-parallelism fix: the compiler collapsed the load batch twice
// (VGPR 36 -> 24), leaving only ~3 loads in flight per wave. sched_barrier(0)
// pins all 8 global_load_dwordx4 BEFORE any consumption -- 32 data VGPRs must
// stay live, giving 32 waves/CU x 8 loads = 256KB in flight per CU.
// VGPR ~48-56 stays under the 64-VGPR cliff -> still 8 waves/SIMD.
#define PAIRS 4

__global__ __launch_bounds__(256, 8) void heatmap_reduce_kernel(
        const float4* __restrict__ pred,
        const float4* __restrict__ gt,
        float* __restrict__ partial, int stride) {
    const int tid = blockIdx.x * 256 + threadIdx.x;

    float4 p[PAIRS], g[PAIRS];

    #pragma unroll
    for (int j = 0; j < PAIRS; ++j) {
        p[j] = pred[tid + j * stride];
        g[j] = gt[tid + j * stride];
    }

    // Fence: no load may sink below this point; all 8 stay in flight.
    __builtin_amdgcn_sched_barrier(0);

    float acc = 0.0f;
    #pragma unroll
    for (int j = 0; j < PAIRS; ++j)
        acc += hterm4(p[j], g[j]);

    #pragma unroll
    for (int off = 32; off > 0; off >>= 1)
        acc += __shfl_down(acc, off, 64);

    __shared__ float wsum[4];
    int lane = threadIdx.x & 63;
    int wave = threadIdx.x >> 6;
    if (lane == 0) wsum[wave] = acc;
    __syncthreads();

    if (threadIdx.x == 0)
        partial[blockIdx.x] = wsum[0] + wsum[1] + wsum[2] + wsum[3];
}

__global__ __launch_bounds__(256) void finalize_kernel(
        const float4* __restrict__ partial4, float* __restrict__ out, int nblocks4) {
    float s = 0.0f;
    for (int i = threadIdx.x; i < nblocks4; i += 256) {
        float4 v = partial4[i];
        s += (v.x + v.y) + (v.z + v.w);
    }

    #pragma unroll
    for (int off = 32; off > 0; off >>= 1)
        s += __shfl_down(s, off, 64);

    __shared__ float wsum[4];
    int lane = threadIdx.x & 63;
    int wave = threadIdx.x >> 6;
    if (lane == 0) wsum[wave] = s;
    __syncthreads();

    if (threadIdx.x == 0)
        out[0] = (wsum[0] + wsum[1] + wsum[2] + wsum[3]) * 0.125f;
}

extern "C" void kernel_launch(void* const* d_in, const int* in_sizes, int n_in,
                              void* d_out, int out_size, void* d_ws, size_t ws_size,
                              hipStream_t stream) {
    const float* pred = (const float*)d_in[0];
    const float* gt   = (const float*)d_in[1];
    float* out     = (float*)d_out;
    float* partial = (float*)d_ws;

    int n  = in_sizes[0];        // 2*8*64*128*128 = 16,777,216
    int n4 = n >> 2;             // 4,194,304 float4s

    const int block  = 256;
    const int grid   = n4 / (block * PAIRS);   // 4096 blocks: 16/CU, 2 rounds of 8
    const int stride = grid * block;           // float4 stride between j-steps

    heatmap_reduce_kernel<<<grid, block, 0, stream>>>(
        (const float4*)pred, (const float4*)gt, partial, stride);

    finalize_kernel<<<1, block, 0, stream>>>(
        (const float4*)partial, out, grid / 4);
}